// Round 7
// baseline (251.215 us; speedup 1.0000x reference)
//
#include <hip/hip_runtime.h>
#include <math.h>

#define H_ 128
#define W_ 160
#define D_ 48
#define C_ 32
#define K27 27
#define HW_ (H_ * W_)
#define DHW_ (D_ * HW_)
#define CHW_ (C_ * HW_)

typedef float f4 __attribute__((ext_vector_type(4)));

// ---------------------------------------------------------------------------
// Kernel 1: projection setup. For each src view v=1..4 store 12 floats:
// rot(9) + trans(3) of  src_proj_new @ inv(ref_proj_new).
// ---------------------------------------------------------------------------
__device__ __forceinline__ void build_proj(const float* __restrict__ P, int v,
                                           double M[4][4]) {
    const float* E = P + (v * 2 + 0) * 16;
    const float* K = P + (v * 2 + 1) * 16;
    for (int i = 0; i < 3; i++)
        for (int j = 0; j < 4; j++) {
            double s = 0.0;
            for (int k = 0; k < 3; k++) s += (double)K[i * 4 + k] * (double)E[k * 4 + j];
            M[i][j] = s;
        }
    for (int j = 0; j < 4; j++) M[3][j] = (double)E[12 + j];
}

__global__ void proj_kernel(const float* __restrict__ P, float* __restrict__ rt) {
    if (threadIdx.x != 0) return;
    double M0[4][4];
    build_proj(P, 0, M0);
    double a[4][8];
    for (int i = 0; i < 4; i++)
        for (int j = 0; j < 4; j++) {
            a[i][j] = M0[i][j];
            a[i][4 + j] = (i == j) ? 1.0 : 0.0;
        }
    for (int col = 0; col < 4; ++col) {
        int piv = col;
        double best = fabs(a[col][col]);
        for (int r = col + 1; r < 4; r++) {
            double vv = fabs(a[r][col]);
            if (vv > best) { best = vv; piv = r; }
        }
        if (piv != col)
            for (int j = 0; j < 8; j++) {
                double t = a[col][j]; a[col][j] = a[piv][j]; a[piv][j] = t;
            }
        double inv = 1.0 / a[col][col];
        for (int j = 0; j < 8; j++) a[col][j] *= inv;
        for (int r = 0; r < 4; r++)
            if (r != col) {
                double f = a[r][col];
                for (int j = 0; j < 8; j++) a[r][j] -= f * a[col][j];
            }
    }
    double Minv[4][4];
    for (int i = 0; i < 4; i++)
        for (int j = 0; j < 4; j++) Minv[i][j] = a[i][4 + j];

    for (int v = 1; v < 5; ++v) {
        double Mv[4][4];
        build_proj(P, v, Mv);
        double Pm[4][4];
        for (int i = 0; i < 4; i++)
            for (int j = 0; j < 4; j++) {
                double s = 0.0;
                for (int k = 0; k < 4; k++) s += Mv[i][k] * Minv[k][j];
                Pm[i][j] = s;
            }
        float* o = rt + (v - 1) * 12;
        o[0] = (float)Pm[0][0]; o[1] = (float)Pm[0][1]; o[2] = (float)Pm[0][2];
        o[3] = (float)Pm[1][0]; o[4] = (float)Pm[1][1]; o[5] = (float)Pm[1][2];
        o[6] = (float)Pm[2][0]; o[7] = (float)Pm[2][1]; o[8] = (float)Pm[2][2];
        o[9] = (float)Pm[0][3]; o[10] = (float)Pm[1][3]; o[11] = (float)Pm[2][3];
    }
}

// ---------------------------------------------------------------------------
// Kernel 1b: transpose both tensors [4][C][HW] -> [4][HW][C] in one launch.
// ---------------------------------------------------------------------------
__global__ void transpose2_kernel(const float* __restrict__ sf,
                                  const float* __restrict__ rf,
                                  float* __restrict__ so,
                                  float* __restrict__ ro) {
    int t = blockIdx.x * blockDim.x + threadIdx.x;
    const float* in = sf;
    float* out = so;
    if (t >= 4 * HW_) {
        t -= 4 * HW_;
        in = rf;
        out = ro;
    }
    int pix = t % HW_;
    int v = t / HW_;
    float vals[C_];
#pragma unroll
    for (int c = 0; c < C_; c++) vals[c] = in[(size_t)v * CHW_ + c * HW_ + pix];
    f4* o = (f4*)(out + ((size_t)v * HW_ + pix) * C_);
#pragma unroll
    for (int q = 0; q < 8; q++) {
        f4 w = {vals[4 * q], vals[4 * q + 1], vals[4 * q + 2], vals[4 * q + 3]};
        o[q] = w;
    }
}

// ---------------------------------------------------------------------------
// Kernel 2: one image row (d,y) per block; 3 batches of 64 voxels x 4
// channel-groups. Round-5 structure (each thread computes its own 4-view
// params -- shfl variant regressed), with per-view linear-in-x coefficients
// hoisted out of the batch loop.
//   phase 1: bilinear+ref blend for 8 channels -> accT LDS
//   phase 2: fold channels through conv weights (wave-uniform taps, SGPR
//            weights) -> gLDS[27][164]
//   phase 3: x-shift-add -> 9 planes Gx (35 MB total)
// ---------------------------------------------------------------------------
__global__ void __launch_bounds__(256)
warp_fold_x_kernel(const float* __restrict__ srcT,
                   const float* __restrict__ refT,
                   const float* __restrict__ rt,
                   const float* __restrict__ dvals,
                   const float* __restrict__ wreg,
                   float* __restrict__ Gx) {
    __shared__ float accT[8][64][4];   // 8 KB
    __shared__ float gLDS[K27][164];   // 17.7 KB

    int t = threadIdx.x;
    int vox = t >> 2;          // 0..63
    int cgrp = t & 3;          // channel group
    int blk = blockIdx.x;      // 0..6143
    int d = blk >> 7;
    int y = blk & 127;
    float depth = dvals[d];
    float yf = (float)y;
    int rowbase = d * HW_ + y * W_;

    // hoisted per-view linear-in-x coefficients (unrolled -> registers)
    float Ax[4], Bx[4], Ay[4], By[4], Az[4], Bz[4];
#pragma unroll
    for (int v = 0; v < 4; v++) {
        const float* m = rt + v * 12;
        Ax[v] = fmaf(fmaf(m[1], yf, m[2]), depth, m[9]);
        Bx[v] = m[0] * depth;
        Ay[v] = fmaf(fmaf(m[4], yf, m[5]), depth, m[10]);
        By[v] = m[3] * depth;
        Az[v] = fmaf(fmaf(m[7], yf, m[8]), depth, m[11]);
        Bz[v] = m[6] * depth;
    }

#pragma unroll 1
    for (int b = 0; b < 3; b++) {
        int vg = b * 64 + vox;            // 0..191
        int x = vg - 1;                   // -1..190 (valid: 0..159)

        f4 acc0 = (f4){0.f, 0.f, 0.f, 0.f};
        f4 acc1 = (f4){0.f, 0.f, 0.f, 0.f};

        if (x >= 0 && x < W_) {
            float xf = (float)x;
            int pix = y * W_ + x;
#pragma unroll 2
            for (int v = 0; v < 4; v++) {
                float pz = fmaf(Bz[v], xf, Az[v]);
                float iz = 1.f / pz;
                float px = fmaf(Bx[v], xf, Ax[v]) * iz;
                float py = fmaf(By[v], xf, Ay[v]) * iz;
                float x0f = floorf(px), y0f = floorf(py);
                float wx = px - x0f, wy = py - y0f;
                int x0 = (int)x0f, y0 = (int)y0f;
                int x1 = x0 + 1, y1 = y0 + 1;

                float w00 = (1.f - wx) * (1.f - wy);
                float w10 = wx * (1.f - wy);
                float w01 = (1.f - wx) * wy;
                float w11 = wx * wy;
                bool vx0 = (x0 >= 0) && (x0 < W_);
                bool vx1 = (x1 >= 0) && (x1 < W_);
                bool vy0 = (y0 >= 0) && (y0 < H_);
                bool vy1 = (y1 >= 0) && (y1 < H_);
                if (!(vx0 && vy0)) w00 = 0.f;
                if (!(vx1 && vy0)) w10 = 0.f;
                if (!(vx0 && vy1)) w01 = 0.f;
                if (!(vx1 && vy1)) w11 = 0.f;
                int cx0 = min(max(x0, 0), W_ - 1);
                int cx1 = min(max(x1, 0), W_ - 1);
                int cy0 = min(max(y0, 0), H_ - 1);
                int cy1 = min(max(y1, 0), H_ - 1);

                const float* sv = srcT + (size_t)v * HW_ * C_ + cgrp * 8;
                const f4* p00 = (const f4*)(sv + (cy0 * W_ + cx0) * C_);
                const f4* p10 = (const f4*)(sv + (cy0 * W_ + cx1) * C_);
                const f4* p01 = (const f4*)(sv + (cy1 * W_ + cx0) * C_);
                const f4* p11 = (const f4*)(sv + (cy1 * W_ + cx1) * C_);
                const f4* pr  = (const f4*)(refT + ((size_t)v * HW_ + pix) * C_ + cgrp * 8);

                f4 a00 = p00[0], b00 = p00[1];
                f4 a10 = p10[0], b10 = p10[1];
                f4 a01 = p01[0], b01 = p01[1];
                f4 a11 = p11[0], b11 = p11[1];
                f4 r0 = pr[0],  r1 = pr[1];

                f4 sv0 = a00 * w00 + a10 * w10 + a01 * w01 + a11 * w11;
                f4 sv1 = b00 * w00 + b10 * w10 + b01 * w01 + b11 * w11;
                acc0 += r0 * sv0;
                acc1 += r1 * sv1;
            }
            acc0 *= 0.25f;
            acc1 *= 0.25f;
        }

        int cq0 = cgrp * 2;
        *(f4*)&accT[cq0][vox][0] = acc0;
        *(f4*)&accT[cq0 + 1][vox][0] = acc1;
        __syncthreads();

        // ---- phase 2: fold channels, wave-uniform tap ranges ----
        int fvox = t & 63;
        int kg = t >> 6;                   // 0..3
        int fvg = b * 64 + fvox;
        float av[C_];
#pragma unroll
        for (int cq = 0; cq < 8; cq++)
            *(f4*)&av[cq * 4] = *(const f4*)&accT[cq][fvox][0];

        if (fvg < 162) {
            int kstart = kg * 7;
            int kend = min(kstart + 7, K27);
#pragma unroll 1
            for (int k = kstart; k < kend; k++) {
                int ku = __builtin_amdgcn_readfirstlane(k);
                float g = 0.f;
#pragma unroll
                for (int c = 0; c < C_; c++) g = fmaf(wreg[c * K27 + ku], av[c], g);
                gLDS[ku][fvg] = g;
            }
        }
        __syncthreads();   // protects accT before next batch overwrites
    }

    // ---- phase 3: x-shift-add -> 9 planes ----
    if (t < W_) {
        int x = t;
#pragma unroll
        for (int j = 0; j < 9; j++) {
            float s = gLDS[j * 3 + 0][x] + gLDS[j * 3 + 1][x + 1] +
                      gLDS[j * 3 + 2][x + 2];
            Gx[(size_t)j * DHW_ + rowbase + x] = s;
        }
    }
}

// ---------------------------------------------------------------------------
// Kernel 3 (fused): gather 9 Gx planes over (d,y) shifts + softmax over D +
// expected depth + windowed confidence. Block = (y, 64-wide x-tile),
// 256 threads = 64 lanes x 4 d-groups (12 d's each). cost stays in registers
// (static-indexed); cross-d-group reduce + exp table via LDS.
// ---------------------------------------------------------------------------
__global__ void __launch_bounds__(256)
gather_softmax_kernel(const float* __restrict__ Gx,
                      const float* __restrict__ dvals,
                      float* __restrict__ out) {
    __shared__ float E[D_][64];       // 12 KB: exp values
    __shared__ float red[4][64];      // block max
    __shared__ float sums[3][4][64];  // s, dnum, inum partials

    int t = threadIdx.x;
    int lx = t & 63;
    int dg = t >> 6;                  // wave-uniform
    int blk = blockIdx.x;
    int xt = blk % 3;
    int y = blk / 3;
    int x = xt * 64 + lx;
    bool xv = x < W_;
    int xc = min(x, W_ - 1);
    int dbase = dg * 12 - 1;

    // S_kd[jj] = sum_kh Gx[kd*3+kh][dbase+jj][y+kh-1][x]
    float S0[14], S1[14], S2[14];
#pragma unroll
    for (int jj = 0; jj < 14; jj++) {
        float s0 = 0.f, s1 = 0.f, s2 = 0.f;
        int dp = dbase + jj;
        if ((unsigned)dp < (unsigned)D_) {
            const float* g0 = Gx + (size_t)dp * HW_ + xc;
#pragma unroll
            for (int kh = 0; kh < 3; kh++) {
                int yy = y + kh - 1;
                if ((unsigned)yy < (unsigned)H_) {
                    const float* gp = g0 + yy * W_ + (size_t)kh * DHW_;
                    s0 += gp[0];
                    s1 += *(gp + (size_t)3 * DHW_);
                    s2 += *(gp + (size_t)6 * DHW_);
                }
            }
        }
        S0[jj] = s0; S1[jj] = s1; S2[jj] = s2;
    }

    float cost[12];
    float lmax = -1e30f;
#pragma unroll
    for (int j = 0; j < 12; j++) {
        cost[j] = S0[j] + S1[j + 1] + S2[j + 2];
        lmax = fmaxf(lmax, cost[j]);
    }
    red[dg][lx] = lmax;
    __syncthreads();
    float mx = fmaxf(fmaxf(red[0][lx], red[1][lx]),
                     fmaxf(red[2][lx], red[3][lx]));

    float s = 0.f, dn = 0.f, din = 0.f;
#pragma unroll
    for (int j = 0; j < 12; j++) {
        int dd = dg * 12 + j;
        float e = __expf(cost[j] - mx);
        E[dd][lx] = e;
        s += e;
        dn = fmaf(e, dvals[dd], dn);
        din = fmaf(e, (float)dd, din);
    }
    sums[0][dg][lx] = s;
    sums[1][dg][lx] = dn;
    sums[2][dg][lx] = din;
    __syncthreads();

    if (dg == 0 && xv) {
        float S = sums[0][0][lx] + sums[0][1][lx] + sums[0][2][lx] + sums[0][3][lx];
        float DN = sums[1][0][lx] + sums[1][1][lx] + sums[1][2][lx] + sums[1][3][lx];
        float DI = sums[2][0][lx] + sums[2][1][lx] + sums[2][2][lx] + sums[2][3][lx];
        float invs = 1.f / S;
        float depth = DN * invs;
        int id = (int)(DI * invs);
        id = min(max(id, 0), D_ - 1);
        float conf = 0.f;
#pragma unroll 1
        for (int k = id - 1; k <= id + 2; ++k)
            if (k >= 0 && k < D_) conf += E[k][lx];
        int pix = y * W_ + x;
        out[pix] = depth;
        out[HW_ + pix] = conf * invs;
    }
}

// ---------------------------------------------------------------------------
extern "C" void kernel_launch(void* const* d_in, const int* in_sizes, int n_in,
                              void* d_out, int out_size, void* d_ws, size_t ws_size,
                              hipStream_t stream) {
    const float* ref_feats = (const float*)d_in[0];   // (4,1,32,128,160)
    const float* src_feats = (const float*)d_in[1];   // (4,1,32,128,160)
    const float* proj      = (const float*)d_in[2];   // (1,5,2,4,4)
    const float* dvals     = (const float*)d_in[3];   // (1,48)
    const float* wreg      = (const float*)d_in[5];   // (1,32,3,3,3)
    float* out = (float*)d_out;                       // depth(20480) ++ conf(20480)

    char* ws = (char*)d_ws;
    float* rt   = (float*)ws;                          // 48 floats (pad to 1KB)
    float* srcT = (float*)(ws + 1024);                 // 10.5 MB
    float* refT = srcT + (size_t)4 * HW_ * C_;         // 10.5 MB
    float* Gx   = refT + (size_t)4 * HW_ * C_;         // 9*DHW*4 = 35.4 MB

    proj_kernel<<<1, 64, 0, stream>>>(proj, rt);
    transpose2_kernel<<<(8 * HW_) / 256, 256, 0, stream>>>(src_feats, ref_feats,
                                                           srcT, refT);
    warp_fold_x_kernel<<<D_ * H_, 256, 0, stream>>>(srcT, refT, rt, dvals, wreg, Gx);
    gather_softmax_kernel<<<3 * H_, 256, 0, stream>>>(Gx, dvals, out);
}

// Round 8
// 222.616 us; speedup vs baseline: 1.1285x; 1.1285x over previous
//
#include <hip/hip_runtime.h>
#include <math.h>

#define H_ 128
#define W_ 160
#define D_ 48
#define C_ 32
#define K27 27
#define HW_ (H_ * W_)
#define DHW_ (D_ * HW_)
#define CHW_ (C_ * HW_)

typedef float f4 __attribute__((ext_vector_type(4)));

// ---------------------------------------------------------------------------
// Projection setup (device function, run by one thread of one block of the
// transpose kernel). For each src view v=1..4 store 12 floats:
// rot(9) + trans(3) of  src_proj_new @ inv(ref_proj_new).
// ---------------------------------------------------------------------------
__device__ __forceinline__ void build_proj(const float* __restrict__ P, int v,
                                           double M[4][4]) {
    const float* E = P + (v * 2 + 0) * 16;
    const float* K = P + (v * 2 + 1) * 16;
    for (int i = 0; i < 3; i++)
        for (int j = 0; j < 4; j++) {
            double s = 0.0;
            for (int k = 0; k < 3; k++) s += (double)K[i * 4 + k] * (double)E[k * 4 + j];
            M[i][j] = s;
        }
    for (int j = 0; j < 4; j++) M[3][j] = (double)E[12 + j];
}

__device__ void do_proj(const float* __restrict__ P, float* __restrict__ rt) {
    double M0[4][4];
    build_proj(P, 0, M0);
    double a[4][8];
    for (int i = 0; i < 4; i++)
        for (int j = 0; j < 4; j++) {
            a[i][j] = M0[i][j];
            a[i][4 + j] = (i == j) ? 1.0 : 0.0;
        }
    for (int col = 0; col < 4; ++col) {
        int piv = col;
        double best = fabs(a[col][col]);
        for (int r = col + 1; r < 4; r++) {
            double vv = fabs(a[r][col]);
            if (vv > best) { best = vv; piv = r; }
        }
        if (piv != col)
            for (int j = 0; j < 8; j++) {
                double t = a[col][j]; a[col][j] = a[piv][j]; a[piv][j] = t;
            }
        double inv = 1.0 / a[col][col];
        for (int j = 0; j < 8; j++) a[col][j] *= inv;
        for (int r = 0; r < 4; r++)
            if (r != col) {
                double f = a[r][col];
                for (int j = 0; j < 8; j++) a[r][j] -= f * a[col][j];
            }
    }
    double Minv[4][4];
    for (int i = 0; i < 4; i++)
        for (int j = 0; j < 4; j++) Minv[i][j] = a[i][4 + j];

    for (int v = 1; v < 5; ++v) {
        double Mv[4][4];
        build_proj(P, v, Mv);
        double Pm[4][4];
        for (int i = 0; i < 4; i++)
            for (int j = 0; j < 4; j++) {
                double s = 0.0;
                for (int k = 0; k < 4; k++) s += Mv[i][k] * Minv[k][j];
                Pm[i][j] = s;
            }
        float* o = rt + (v - 1) * 12;
        o[0] = (float)Pm[0][0]; o[1] = (float)Pm[0][1]; o[2] = (float)Pm[0][2];
        o[3] = (float)Pm[1][0]; o[4] = (float)Pm[1][1]; o[5] = (float)Pm[1][2];
        o[6] = (float)Pm[2][0]; o[7] = (float)Pm[2][1]; o[8] = (float)Pm[2][2];
        o[9] = (float)Pm[0][3]; o[10] = (float)Pm[1][3]; o[11] = (float)Pm[2][3];
    }
}

// ---------------------------------------------------------------------------
// Kernel 1: LDS-staged transpose [4][C][HW] -> [4][HW][C] for both tensors,
// fully coalesced reads AND writes. 2560 tile-blocks + 1 proj block.
// Tile = 64 pixels x 32 channels per block.
// ---------------------------------------------------------------------------
__global__ void __launch_bounds__(256)
transpose2_kernel(const float* __restrict__ sf, const float* __restrict__ rf,
                  float* __restrict__ so, float* __restrict__ ro,
                  const float* __restrict__ P, float* __restrict__ rt) {
    int blk = blockIdx.x;
    if (blk >= 2560) {
        if (threadIdx.x == 0) do_proj(P, rt);
        return;
    }
    __shared__ float tile[C_][65];
    int t = threadIdx.x;
    int tv = blk / 320;            // 0..7: tensor(2) x view(4)
    int tileI = blk % 320;
    int pixbase = tileI * 64;
    const float* in = (tv < 4) ? sf : rf;
    float* out = (tv < 4) ? so : ro;
    int v = tv & 3;

    // read: lane = pixel, 8 channels per thread (coalesced 256B/instr)
    int pix = t & 63;
    int cbase = (t >> 6) * 8;
#pragma unroll
    for (int cc = 0; cc < 8; cc++) {
        int c = cbase + cc;
        tile[c][pix] = in[(size_t)v * CHW_ + c * HW_ + pixbase + pix];
    }
    __syncthreads();

    // write: flat f4 index, lanes contiguous (coalesced 4KB/instr)
    float* obase = out + ((size_t)v * HW_ + pixbase) * C_;
#pragma unroll
    for (int r = 0; r < 2; r++) {
        int i = r * 256 + t;       // f4 index 0..511
        int wpix = i >> 3;
        int c0 = (i & 7) * 4;
        f4 w = {tile[c0][wpix], tile[c0 + 1][wpix], tile[c0 + 2][wpix],
                tile[c0 + 3][wpix]};
        *(f4*)(obase + (size_t)wpix * C_ + c0) = w;
    }
}

// ---------------------------------------------------------------------------
// Kernel 2: one image row (d,y) per block; 3 batches of 64 voxels x 4
// channel-groups. EXACT round-5 phase-1 (measured 121us; hoisted-array and
// shfl variants both regressed).
//   phase 1: bilinear+ref blend for 8 channels -> accT LDS
//   phase 2: fold channels through conv weights (wave-uniform taps, SGPR
//            weights) -> gLDS[27][164]
//   phase 3: x-shift-add -> 9 planes Gx (35 MB total)
// ---------------------------------------------------------------------------
__global__ void __launch_bounds__(256)
warp_fold_x_kernel(const float* __restrict__ srcT,
                   const float* __restrict__ refT,
                   const float* __restrict__ rt,
                   const float* __restrict__ dvals,
                   const float* __restrict__ wreg,
                   float* __restrict__ Gx) {
    __shared__ float accT[8][64][4];   // 8 KB
    __shared__ float gLDS[K27][164];   // 17.7 KB

    int t = threadIdx.x;
    int vox = t >> 2;          // 0..63
    int cgrp = t & 3;          // channel group
    int blk = blockIdx.x;      // 0..6143
    int d = blk >> 7;
    int y = blk & 127;
    float depth = dvals[d];
    float yf = (float)y;
    int rowbase = d * HW_ + y * W_;

#pragma unroll 1
    for (int b = 0; b < 3; b++) {
        int vg = b * 64 + vox;            // 0..191
        int x = vg - 1;                   // -1..190 (valid: 0..159)

        f4 acc0 = (f4){0.f, 0.f, 0.f, 0.f};
        f4 acc1 = (f4){0.f, 0.f, 0.f, 0.f};

        if (x >= 0 && x < W_) {
            float xf = (float)x;
            int pix = y * W_ + x;
#pragma unroll 2
            for (int v = 0; v < 4; v++) {
                const float* m = rt + v * 12;
                float px = fmaf(fmaf(m[0], xf, fmaf(m[1], yf, m[2])), depth, m[9]);
                float py = fmaf(fmaf(m[3], xf, fmaf(m[4], yf, m[5])), depth, m[10]);
                float pz = fmaf(fmaf(m[6], xf, fmaf(m[7], yf, m[8])), depth, m[11]);
                float iz = 1.f / pz;
                px *= iz;
                py *= iz;
                float x0f = floorf(px), y0f = floorf(py);
                float wx = px - x0f, wy = py - y0f;
                int x0 = (int)x0f, y0 = (int)y0f;
                int x1 = x0 + 1, y1 = y0 + 1;

                float w00 = (1.f - wx) * (1.f - wy);
                float w10 = wx * (1.f - wy);
                float w01 = (1.f - wx) * wy;
                float w11 = wx * wy;
                bool vx0 = (x0 >= 0) && (x0 < W_);
                bool vx1 = (x1 >= 0) && (x1 < W_);
                bool vy0 = (y0 >= 0) && (y0 < H_);
                bool vy1 = (y1 >= 0) && (y1 < H_);
                if (!(vx0 && vy0)) w00 = 0.f;
                if (!(vx1 && vy0)) w10 = 0.f;
                if (!(vx0 && vy1)) w01 = 0.f;
                if (!(vx1 && vy1)) w11 = 0.f;
                int cx0 = min(max(x0, 0), W_ - 1);
                int cx1 = min(max(x1, 0), W_ - 1);
                int cy0 = min(max(y0, 0), H_ - 1);
                int cy1 = min(max(y1, 0), H_ - 1);

                const float* sv = srcT + (size_t)v * HW_ * C_ + cgrp * 8;
                const f4* p00 = (const f4*)(sv + (cy0 * W_ + cx0) * C_);
                const f4* p10 = (const f4*)(sv + (cy0 * W_ + cx1) * C_);
                const f4* p01 = (const f4*)(sv + (cy1 * W_ + cx0) * C_);
                const f4* p11 = (const f4*)(sv + (cy1 * W_ + cx1) * C_);
                const f4* pr  = (const f4*)(refT + ((size_t)v * HW_ + pix) * C_ + cgrp * 8);

                f4 a00 = p00[0], b00 = p00[1];
                f4 a10 = p10[0], b10 = p10[1];
                f4 a01 = p01[0], b01 = p01[1];
                f4 a11 = p11[0], b11 = p11[1];
                f4 r0 = pr[0],  r1 = pr[1];

                f4 sv0 = a00 * w00 + a10 * w10 + a01 * w01 + a11 * w11;
                f4 sv1 = b00 * w00 + b10 * w10 + b01 * w01 + b11 * w11;
                acc0 += r0 * sv0;
                acc1 += r1 * sv1;
            }
            acc0 *= 0.25f;
            acc1 *= 0.25f;
        }

        int cq0 = cgrp * 2;
        *(f4*)&accT[cq0][vox][0] = acc0;
        *(f4*)&accT[cq0 + 1][vox][0] = acc1;
        __syncthreads();

        // ---- phase 2: fold channels, wave-uniform tap ranges ----
        int fvox = t & 63;
        int kg = t >> 6;                   // 0..3
        int fvg = b * 64 + fvox;
        float av[C_];
#pragma unroll
        for (int cq = 0; cq < 8; cq++)
            *(f4*)&av[cq * 4] = *(const f4*)&accT[cq][fvox][0];

        if (fvg < 162) {
            int kstart = kg * 7;
            int kend = min(kstart + 7, K27);
#pragma unroll 1
            for (int k = kstart; k < kend; k++) {
                int ku = __builtin_amdgcn_readfirstlane(k);
                float g = 0.f;
#pragma unroll
                for (int c = 0; c < C_; c++) g = fmaf(wreg[c * K27 + ku], av[c], g);
                gLDS[ku][fvg] = g;
            }
        }
        __syncthreads();   // protects accT before next batch overwrites
    }

    // ---- phase 3: x-shift-add -> 9 planes ----
    if (t < W_) {
        int x = t;
#pragma unroll
        for (int j = 0; j < 9; j++) {
            float s = gLDS[j * 3 + 0][x] + gLDS[j * 3 + 1][x + 1] +
                      gLDS[j * 3 + 2][x + 2];
            Gx[(size_t)j * DHW_ + rowbase + x] = s;
        }
    }
}

// ---------------------------------------------------------------------------
// Kernel 3 (fused): gather 9 Gx planes over (d,y) shifts + softmax over D +
// expected depth + windowed confidence. Block = (y, 64-wide x-tile),
// 512 threads = 64 lanes x 8 d-groups (6 d's each) for latency hiding.
// ---------------------------------------------------------------------------
__global__ void __launch_bounds__(512)
gather_softmax_kernel(const float* __restrict__ Gx,
                      const float* __restrict__ dvals,
                      float* __restrict__ out) {
    __shared__ float E[D_][64];        // 12 KB: exp values
    __shared__ float red[8][64];       // block max
    __shared__ float sums[3][8][64];   // s, dnum, inum partials

    int t = threadIdx.x;
    int lx = t & 63;
    int dg = t >> 6;                  // 0..7, wave-uniform
    int blk = blockIdx.x;
    int xt = blk % 3;
    int y = blk / 3;
    int x = xt * 64 + lx;
    bool xv = x < W_;
    int xc = min(x, W_ - 1);
    int dbase = dg * 6 - 1;

    // S_kd[jj] = sum_kh Gx[kd*3+kh][dbase+jj][y+kh-1][x]
    float S0[8], S1[8], S2[8];
#pragma unroll
    for (int jj = 0; jj < 8; jj++) {
        float s0 = 0.f, s1 = 0.f, s2 = 0.f;
        int dp = dbase + jj;
        if ((unsigned)dp < (unsigned)D_) {
            const float* g0 = Gx + (size_t)dp * HW_ + xc;
#pragma unroll
            for (int kh = 0; kh < 3; kh++) {
                int yy = y + kh - 1;
                if ((unsigned)yy < (unsigned)H_) {
                    const float* gp = g0 + yy * W_ + (size_t)kh * DHW_;
                    s0 += gp[0];
                    s1 += *(gp + (size_t)3 * DHW_);
                    s2 += *(gp + (size_t)6 * DHW_);
                }
            }
        }
        S0[jj] = s0; S1[jj] = s1; S2[jj] = s2;
    }

    float cost[6];
    float lmax = -1e30f;
#pragma unroll
    for (int j = 0; j < 6; j++) {
        cost[j] = S0[j] + S1[j + 1] + S2[j + 2];
        lmax = fmaxf(lmax, cost[j]);
    }
    red[dg][lx] = lmax;
    __syncthreads();
    float mx = red[0][lx];
#pragma unroll
    for (int g = 1; g < 8; g++) mx = fmaxf(mx, red[g][lx]);

    float s = 0.f, dn = 0.f, din = 0.f;
#pragma unroll
    for (int j = 0; j < 6; j++) {
        int dd = dg * 6 + j;
        float e = __expf(cost[j] - mx);
        E[dd][lx] = e;
        s += e;
        dn = fmaf(e, dvals[dd], dn);
        din = fmaf(e, (float)dd, din);
    }
    sums[0][dg][lx] = s;
    sums[1][dg][lx] = dn;
    sums[2][dg][lx] = din;
    __syncthreads();

    if (dg == 0 && xv) {
        float S = 0.f, DN = 0.f, DI = 0.f;
#pragma unroll
        for (int g = 0; g < 8; g++) {
            S += sums[0][g][lx];
            DN += sums[1][g][lx];
            DI += sums[2][g][lx];
        }
        float invs = 1.f / S;
        float depth = DN * invs;
        int id = (int)(DI * invs);
        id = min(max(id, 0), D_ - 1);
        float conf = 0.f;
#pragma unroll 1
        for (int k = id - 1; k <= id + 2; ++k)
            if (k >= 0 && k < D_) conf += E[k][lx];
        int pix = y * W_ + x;
        out[pix] = depth;
        out[HW_ + pix] = conf * invs;
    }
}

// ---------------------------------------------------------------------------
extern "C" void kernel_launch(void* const* d_in, const int* in_sizes, int n_in,
                              void* d_out, int out_size, void* d_ws, size_t ws_size,
                              hipStream_t stream) {
    const float* ref_feats = (const float*)d_in[0];   // (4,1,32,128,160)
    const float* src_feats = (const float*)d_in[1];   // (4,1,32,128,160)
    const float* proj      = (const float*)d_in[2];   // (1,5,2,4,4)
    const float* dvals     = (const float*)d_in[3];   // (1,48)
    const float* wreg      = (const float*)d_in[5];   // (1,32,3,3,3)
    float* out = (float*)d_out;                       // depth(20480) ++ conf(20480)

    char* ws = (char*)d_ws;
    float* rt   = (float*)ws;                          // 48 floats (pad to 1KB)
    float* srcT = (float*)(ws + 1024);                 // 10.5 MB
    float* refT = srcT + (size_t)4 * HW_ * C_;         // 10.5 MB
    float* Gx   = refT + (size_t)4 * HW_ * C_;         // 9*DHW*4 = 35.4 MB

    transpose2_kernel<<<2561, 256, 0, stream>>>(src_feats, ref_feats, srcT, refT,
                                                proj, rt);
    warp_fold_x_kernel<<<D_ * H_, 256, 0, stream>>>(srcT, refT, rt, dvals, wreg, Gx);
    gather_softmax_kernel<<<3 * H_, 512, 0, stream>>>(Gx, dvals, out);
}